// Round 4
// baseline (418.712 us; speedup 1.0000x reference)
//
#include <hip/hip_runtime.h>
#include <stdint.h>

typedef __bf16 bf16x8 __attribute__((ext_vector_type(8)));
typedef __bf16 bf16x4 __attribute__((ext_vector_type(4)));
typedef float  f32x4  __attribute__((ext_vector_type(4)));

#define MTOT 16384
#define G_NCH 16       // gram chunks per batch -> 32*16 = 512 blocks
#define G_CHUNK 1024   // m-columns per gram block (4 supersteps of 256)
#define TSTR 264       // bf16 tile stride (256+8)

// ---------------- Kernel 1: diff stream. One block per (b,c) row = 64 KB contiguous span.
// diff = x - prev (f32, written into d_out as scratch) + full row-sum -> mus[row].
__global__ __launch_bounds__(256) void diff_k(const float* __restrict__ x,
                                              const float* __restrict__ prev,
                                              float* __restrict__ diff,
                                              float* __restrict__ mus) {
  const int row = blockIdx.x;            // 0..2047  (b*64 + c)
  const int tid = threadIdx.x;
  const size_t b4 = (size_t)row * (MTOT / 4);
  float s = 0.f;
#pragma unroll
  for (int it = 0; it < 16; ++it) {
    const size_t f = b4 + it * 256 + tid;
    float4 a = ((const float4*)x)[f];
    float4 p = ((const float4*)prev)[f];
    float4 d;
    d.x = a.x - p.x; d.y = a.y - p.y; d.z = a.z - p.z; d.w = a.w - p.w;
    ((float4*)diff)[f] = d;
    s += (d.x + d.y) + (d.z + d.w);
  }
  s += __shfl_xor(s, 1);  s += __shfl_xor(s, 2);  s += __shfl_xor(s, 4);
  s += __shfl_xor(s, 8);  s += __shfl_xor(s, 16); s += __shfl_xor(s, 32);
  __shared__ float sw[4];
  if ((tid & 63) == 0) sw[tid >> 6] = s;
  __syncthreads();
  if (tid == 0) mus[row] = sw[0] + sw[1] + sw[2] + sw[3];
}

// ---------------- Kernel 2: Gram partials from L3-resident f32 diff.
// Register-double-buffered prefetch: superstep s+1's 8 loads issue before cvt/MFMA of s.
__global__ __launch_bounds__(512) void gram_k(const float* __restrict__ diff,
                                              float* __restrict__ Gpart) {
  __shared__ __bf16 tile[64 * TSTR];     // 33792 B
  const int tid  = threadIdx.x;
  const int wv   = tid >> 6;             // 0..7
  const int lane = tid & 63;
  const int b    = blockIdx.x >> 4;
  const int ch   = blockIdx.x & 15;
  const size_t base = (size_t)b * 64 * MTOT + (size_t)ch * G_CHUNK;
  const int arow = wv >> 1;              // MFMA row-strip 0..3
  const int bc0  = (wv & 1) * 2;         // MFMA col-strips bc0, bc0+1

  f32x4 acc[2];
  acc[0] = (f32x4){0.f,0.f,0.f,0.f};
  acc[1] = (f32x4){0.f,0.f,0.f,0.f};

  const float* db = diff + base + (size_t)(wv * 8) * MTOT + lane * 4;

  float4 xr[2][8];
#pragma unroll
  for (int i = 0; i < 8; ++i) xr[0][i] = *(const float4*)(db + (size_t)i * MTOT);

#pragma unroll
  for (int ss = 0; ss < 4; ++ss) {       // 4 supersteps x 256 cols
    const int cur = ss & 1;              // compile-time after unroll (rule #20)
    if (ss < 3) {
#pragma unroll
      for (int i = 0; i < 8; ++i)
        xr[cur ^ 1][i] = *(const float4*)(db + (size_t)i * MTOT + (ss + 1) * 256);
    }
#pragma unroll
    for (int i = 0; i < 8; ++i) {
      float4 v = xr[cur][i];
      bf16x4 q = {(__bf16)v.x, (__bf16)v.y, (__bf16)v.z, (__bf16)v.w};
      *(bf16x4*)&tile[(wv * 8 + i) * TSTR + lane * 4] = q;
    }
    __syncthreads();
    // syrk over the 64x256 tile: 8 K-slices of 32
#pragma unroll
    for (int ks = 0; ks < 8; ++ks) {
      const int mloc = ks * 32 + (lane >> 4) * 8;
      const int r    = lane & 15;
      bf16x8 fa  = *(const bf16x8*)&tile[(arow * 16 + r) * TSTR + mloc];
      bf16x8 fb0 = *(const bf16x8*)&tile[(bc0 * 16 + r) * TSTR + mloc];
      bf16x8 fb1 = *(const bf16x8*)&tile[((bc0 + 1) * 16 + r) * TSTR + mloc];
      acc[0] = __builtin_amdgcn_mfma_f32_16x16x32_bf16(fa, fb0, acc[0], 0, 0, 0);
      acc[1] = __builtin_amdgcn_mfma_f32_16x16x32_bf16(fa, fb1, acc[1], 0, 0, 0);
    }
    __syncthreads();
  }

  float* gp = Gpart + (size_t)blockIdx.x * 4096;
  const int r4 = (lane >> 4) * 4;
  const int c  = lane & 15;
#pragma unroll
  for (int t = 0; t < 2; ++t)
#pragma unroll
    for (int rr = 0; rr < 4; ++rr)
      gp[(arow * 16 + r4 + rr) * 64 + (bc0 + t) * 16 + c] = acc[t][rr];
}

// ---------------- 64x64 f32 matmul in LDS (stride 68), 4x4 tile, 256 threads
__device__ __forceinline__ void mm64(float* __restrict__ D, const float* __restrict__ A,
                                     const float* __restrict__ B, int t, bool nsform) {
  const int i0 = (t >> 4) * 4;
  const int j0 = (t & 15) * 4;
  float accv[4][4] = {};
  for (int kq = 0; kq < 16; ++kq) {
    float4 av[4], bv[4];
#pragma unroll
    for (int r = 0; r < 4; ++r) av[r] = *(const float4*)&A[(i0 + r) * 68 + kq * 4];
#pragma unroll
    for (int r = 0; r < 4; ++r) bv[r] = *(const float4*)&B[(kq * 4 + r) * 68 + j0];
#pragma unroll
    for (int r = 0; r < 4; ++r) {
      const float ar[4] = {av[r].x, av[r].y, av[r].z, av[r].w};
#pragma unroll
      for (int q = 0; q < 4; ++q) {
        const float bq[4] = {bv[q].x, bv[q].y, bv[q].z, bv[q].w};
#pragma unroll
        for (int cc = 0; cc < 4; ++cc)
          accv[r][cc] = fmaf(ar[q], bq[cc], accv[r][cc]);
      }
    }
  }
#pragma unroll
  for (int r = 0; r < 4; ++r)
#pragma unroll
    for (int cc = 0; cc < 4; ++cc) {
      float v = accv[r][cc];
      if (nsform) v = ((i0 + r) == (j0 + cc) ? 1.5f : 0.f) - 0.5f * v;  // 0.5*(3I - P)
      D[(i0 + r) * 68 + j0 + cc] = v;
    }
}

// ---------------- Kernel 3: per-batch cov assembly + Newton-Schulz + MLP gate
__global__ __launch_bounds__(256) void ns_k(const float* __restrict__ Gpart,
                                            const float* __restrict__ mus,
                                            const float* __restrict__ w1, const float* __restrict__ b1,
                                            const float* __restrict__ w2, const float* __restrict__ b2,
                                            float* __restrict__ yout) {
  __shared__ float bufs[6][64 * 68];   // ~104.4 KB
  __shared__ float smu[64], sS[64], sh[8], snorm;
  const int b = blockIdx.x, tid = threadIdx.x;

  if (tid < 64) smu[tid] = mus[b * 64 + tid] * (1.f / 16384.f);
  __syncthreads();
  for (int e = tid; e < 4096; e += 256) {
    int i = e >> 6, j = e & 63;
    float g = 0.f;
    for (int p = 0; p < G_NCH; ++p) g += Gpart[(size_t)(b * G_NCH + p) * 4096 + e];
    bufs[0][i * 68 + j] = g * (1.f / 16384.f) - smu[i] * smu[j];
  }
  __syncthreads();
  if (tid < 64) {
    float v = bufs[0][tid * 68 + tid];
    for (int off = 32; off; off >>= 1) v += __shfl_down(v, off);
    if (tid == 0) snorm = v;
  }
  __syncthreads();
  const float normA = snorm;
  const float inv = 1.f / normA;
  for (int e = tid; e < 4096; e += 256) {
    int i = e >> 6, j = e & 63;
    float an = bufs[0][i * 68 + j] * inv;
    bufs[0][i * 68 + j] = an;
    bufs[1][i * 68 + j] = 0.5f * ((i == j ? 3.f : 0.f) - an);
  }
  __syncthreads();
  mm64(bufs[2], bufs[0], bufs[1], tid, false);   // Y = An @ ZY0
  __syncthreads();
  float *Y = bufs[2], *Z = bufs[1], *Yn = bufs[4], *Zn = bufs[5];
  for (int it = 0; it < 3; ++it) {
    mm64(bufs[3], Z, Y, tid, true);              // ZY = 0.5*(3I - Z@Y)
    __syncthreads();
    mm64(Yn, Y, bufs[3], tid, false);            // Y' = Y @ ZY
    mm64(Zn, bufs[3], Z, tid, false);            // Z' = ZY @ Z
    __syncthreads();
    float* t0 = Y; Y = Yn; Yn = t0;
    float* t1 = Z; Z = Zn; Zn = t1;
  }
  mm64(bufs[3], Z, Y, tid, true);
  __syncthreads();
  mm64(Yn, Y, bufs[3], tid, false);              // YZY
  __syncthreads();
  if (tid < 64) {
    float s = 0.f;
    for (int i = 0; i < 64; ++i) s += Yn[i * 68 + tid];
    sS[tid] = s * (1.f / 64.f) * sqrtf(normA);
  }
  __syncthreads();
  if (tid < 8) {
    float h = b1[tid];
    for (int c2 = 0; c2 < 64; ++c2) h += w1[tid * 64 + c2] * sS[c2];
    sh[tid] = fmaxf(h, 0.f);
  }
  __syncthreads();
  if (tid < 64) {
    float l = b2[tid];
    for (int o = 0; o < 8; ++o) l += w2[tid * 8 + o] * sh[o];
    yout[b * 64 + tid] = 1.f / (1.f + expf(-l));
  }
}

// ---------------- Kernel 4: in-place scale of diff (in d_out) by y[row]
__global__ __launch_bounds__(256) void scale_k(float* __restrict__ io,
                                               const float* __restrict__ y) {
  const int row = blockIdx.x;            // b*64 + c
  const float s = y[row];
  const size_t b4 = (size_t)row * (MTOT / 4);
#pragma unroll
  for (int it = 0; it < 16; ++it) {
    const size_t f = b4 + it * 256 + threadIdx.x;
    float4 v = ((float4*)io)[f];
    v.x *= s; v.y *= s; v.z *= s; v.w *= s;
    ((float4*)io)[f] = v;
  }
}

extern "C" void kernel_launch(void* const* d_in, const int* in_sizes, int n_in,
                              void* d_out, int out_size, void* d_ws, size_t ws_size,
                              hipStream_t stream) {
  (void)in_sizes; (void)n_in; (void)out_size; (void)ws_size;
  const float* prev = (const float*)d_in[0];
  const float* x    = (const float*)d_in[1];
  const float* w1   = (const float*)d_in[2];
  const float* b1   = (const float*)d_in[3];
  const float* w2   = (const float*)d_in[4];
  const float* b2   = (const float*)d_in[5];
  float* out = (float*)d_out;            // doubles as f32 diff scratch

  float* Gpart = (float*)d_ws;                       // 512*4096 f32 = 8 MB
  float* mus   = Gpart + (size_t)512 * 4096;         // 2048 f32
  float* yv    = mus + 2048;                         // 2048 f32

  diff_k<<<2048, 256, 0, stream>>>(x, prev, out, mus);
  gram_k<<<512, 512, 0, stream>>>(out, Gpart);
  ns_k<<<32, 256, 0, stream>>>(Gpart, mus, w1, b1, w2, b2, yv);
  scale_k<<<2048, 256, 0, stream>>>(out, yv);
}